// Round 2
// baseline (650.901 us; speedup 1.0000x reference)
//
#include <hip/hip_runtime.h>
#include <math.h>

#define B_ 4
#define T_ 16
#define H_ 64
#define W_ 64
#define CIN 32
#define CO 64
#define NG 256   // 4*CO gate channels
#define PXS 40   // padded per-pixel stride in shorts (80 B): 16B-aligned, spreads LDS banks

typedef __attribute__((ext_vector_type(8))) short bf16x8;
typedef __attribute__((ext_vector_type(4))) float f32x4;

__device__ __forceinline__ float hsig(float z) {
    return fminf(1.f, fmaxf(0.f, 0.2f * z + 0.5f));
}

// fast tanh: v_exp_f32 + v_rcp_f32. Saturation exact at +/-inf.
__device__ __forceinline__ float ftanh(float x) {
    float e = __builtin_amdgcn_exp2f(x * 2.8853900817779268f);  // 2*log2(e)
    return 1.f - 2.f * __builtin_amdgcn_rcpf(e + 1.f);
}

__device__ __forceinline__ unsigned short f2bf(float f) {
    union { float f; unsigned u; } v; v.f = f;
    unsigned r = v.u + 0x7FFFu + ((v.u >> 16) & 1u);   // RTNE
    return (unsigned short)(r >> 16);
}

// Transpose+convert weights once per launch; also zero the tile flags.
//   wkT[kpos][n=256][k=32]        from wk (3,3,32,256)
//   wrT[kpos][q=2][n=256][k=32]   from wr (3,3,64,256), q = cin chunk of 32
__global__ void transform_weights(const float* __restrict__ wk,
                                  const float* __restrict__ wr,
                                  unsigned short* __restrict__ wkT,
                                  unsigned short* __restrict__ wrT,
                                  int* __restrict__ flags)
{
    int i = blockIdx.x * 256 + threadIdx.x;
    if (i < 9 * 256 * 32) {
        int k = i & 31, n = (i >> 5) & 255, kpos = i >> 13;
        wkT[i] = f2bf(wk[(kpos * 32 + k) * 256 + n]);
    }
    if (i < 9 * 2 * 256 * 32) {
        int k = i & 31, n = (i >> 5) & 255, q = (i >> 13) & 1, kpos = i >> 14;
        wrT[i] = f2bf(wr[(kpos * 64 + q * 32 + k) * 256 + n]);
    }
    if (i < 256 * 16) flags[i] = 0;
}

// One timestep of the persistent kernel. Block = 64 px (4 rows x 16 cols),
// all 256 gate channels; wave w owns channels w*16+(lane&15).
// Cross-block h / flags move ONLY via relaxed AGENT-scope atomics (sc-bit
// coherent accesses) -> no cache-wide inv/wb, weights stay L2-resident.
template<bool FIRST>
__device__ __forceinline__ void do_step(
    int t, int tid, int ln, int kg, int b, int oy, int ox,
    const float* __restrict__ x,
    const unsigned short* wkp, const unsigned short* wrp,
    const float* hin, float* hout, float* __restrict__ out,
    unsigned short* sx, unsigned short* sh0, unsigned short* sh1,
    int* nbf, int* myflag,
    float bi0, float bi1, float bi2, float bi3, float inv, float shift,
    int ch, float (&creg)[4][4])
{
    // ---- stage x halo (fp32 -> bf16): 108 positions x 4 chunks of 8 cin ----
    // Issued BEFORE the neighbor spin so the loads' latency hides under it.
#pragma unroll
    for (int i = 0; i < 2; ++i) {
        int e = tid + i * 256;
        if (e < 432) {
            int c8 = e & 3, p = e >> 2;
            int row = p / 18, col = p - row * 18;
            int gy = oy - 1 + row, gx = ox - 1 + col;
            float4 v0 = make_float4(0.f, 0.f, 0.f, 0.f), v1 = v0;
            if ((unsigned)gy < (unsigned)H_ && (unsigned)gx < (unsigned)W_) {
                const float* p32 = &x[((((size_t)b * T_ + t) * H_ + gy) * W_ + gx) * CIN + c8 * 8];
                v0 = *(const float4*)p32; v1 = *(const float4*)(p32 + 4);
            }
            unsigned short* d = &sx[(row * 18 + col) * PXS + c8 * 8];
            d[0] = f2bf(v0.x); d[1] = f2bf(v0.y); d[2] = f2bf(v0.z); d[3] = f2bf(v0.w);
            d[4] = f2bf(v1.x); d[5] = f2bf(v1.y); d[6] = f2bf(v1.z); d[7] = f2bf(v1.w);
        }
    }

    // ---- wait for the 8 spatial neighbors to have published h(t-1) ----
    if (!FIRST) {
        if (nbf) {
            while (__hip_atomic_load(nbf, __ATOMIC_RELAXED, __HIP_MEMORY_SCOPE_AGENT) < t)
                __builtin_amdgcn_s_sleep(2);
        }
        __syncthreads();
        // ---- stage h(t-1) halo (fp32 agent-coherent load -> bf16 in LDS) ----
        // 108 positions x 32 pairs of 2 channels = 3456 8-byte loads.
#pragma unroll
        for (int i = 0; i < 14; ++i) {
            int e = tid + i * 256;
            if (e < 3456) {
                int pr = e & 31, p = e >> 5;       // pr: channel pair, ch = 2*pr
                int row = p / 18, col = p - row * 18;
                int gy = oy - 1 + row, gx = ox - 1 + col;
                unsigned long long uv = 0ull;
                if ((unsigned)gy < (unsigned)H_ && (unsigned)gx < (unsigned)W_)
                    uv = __hip_atomic_load(
                        (unsigned long long*)(hin + (((size_t)b * H_ + gy) * W_ + gx) * CO + pr * 2),
                        __ATOMIC_RELAXED, __HIP_MEMORY_SCOPE_AGENT);
                union { unsigned u; float f; } w0, w1;
                w0.u = (unsigned)uv; w1.u = (unsigned)(uv >> 32);
                unsigned pack = (unsigned)f2bf(w0.f) | ((unsigned)f2bf(w1.f) << 16);
                int cch = pr * 2;
                unsigned short* dst = (cch < 32) ? sh0 : sh1;
                *(unsigned*)&dst[(row * 18 + col) * PXS + (cch & 31)] = pack;
            }
        }
    }
    __syncthreads();

    // ---- K-loop: fully unrolled 9 kpos, dist-1 register prefetch of B ----
    f32x4 acc[4][4];   // [gate][row-tile]
#pragma unroll
    for (int g = 0; g < 4; ++g)
#pragma unroll
        for (int r = 0; r < 4; ++r) acc[g][r] = (f32x4){0.f, 0.f, 0.f, 0.f};

    bf16x8 bx[4], bh[2][4];
#pragma unroll
    for (int g = 0; g < 4; ++g)
        bx[g] = *(const bf16x8*)(wkp + (size_t)(g * 64) * 32);
    if (!FIRST) {
#pragma unroll
        for (int q = 0; q < 2; ++q)
#pragma unroll
            for (int g = 0; g < 4; ++g)
                bh[q][g] = *(const bf16x8*)(wrp + (size_t)(q * 256 + g * 64) * 32);
    }

#pragma unroll
    for (int kpos = 0; kpos < 9; ++kpos) {
        const int ky = kpos / 3, kx = kpos - ky * 3;
        bf16x8 nbx[4], nbh[2][4];
        if (kpos < 8) {
#pragma unroll
            for (int g = 0; g < 4; ++g)
                nbx[g] = *(const bf16x8*)(wkp + (size_t)((kpos + 1) * 256 + g * 64) * 32);
            if (!FIRST) {
#pragma unroll
                for (int q = 0; q < 2; ++q)
#pragma unroll
                    for (int g = 0; g < 4; ++g)
                        nbh[q][g] = *(const bf16x8*)(wrp + (size_t)(((kpos + 1) * 2 + q) * 256 + g * 64) * 32);
            }
        }
        bf16x8 a[4];
#pragma unroll
        for (int r = 0; r < 4; ++r)
            a[r] = *(const bf16x8*)&sx[((r + ky) * 18 + ln + kx) * PXS + kg * 8];
#pragma unroll
        for (int g = 0; g < 4; ++g)
#pragma unroll
            for (int r = 0; r < 4; ++r)
                acc[g][r] = __builtin_amdgcn_mfma_f32_16x16x32_bf16(a[r], bx[g], acc[g][r], 0, 0, 0);
        if (!FIRST) {
#pragma unroll
            for (int q = 0; q < 2; ++q) {
                unsigned short* shq = q ? sh1 : sh0;
#pragma unroll
                for (int r = 0; r < 4; ++r)
                    a[r] = *(const bf16x8*)&shq[((r + ky) * 18 + ln + kx) * PXS + kg * 8];
#pragma unroll
                for (int g = 0; g < 4; ++g)
#pragma unroll
                    for (int r = 0; r < 4; ++r)
                        acc[g][r] = __builtin_amdgcn_mfma_f32_16x16x32_bf16(a[r], bh[q][g], acc[g][r], 0, 0, 0);
            }
        }
        if (kpos < 8) {
#pragma unroll
            for (int g = 0; g < 4; ++g) bx[g] = nbx[g];
            if (!FIRST) {
#pragma unroll
                for (int q = 0; q < 2; ++q)
#pragma unroll
                    for (int g = 0; g < 4; ++g) bh[q][g] = nbh[q][g];
            }
        }
    }

    // ---- epilogue: gates, c in registers, publish h, write out ----
#pragma unroll
    for (int r = 0; r < 4; ++r) {
        const int gy = oy + r;
#pragma unroll
        for (int reg = 0; reg < 4; ++reg) {
            const int gx = ox + kg * 4 + reg;
            size_t pix = ((size_t)b * H_ + gy) * W_ + gx;
            float ig = hsig(acc[0][r][reg] + bi0);
            float fg = hsig(acc[1][r][reg] + bi1);
            float cg = ftanh(acc[2][r][reg] + bi2);
            float og = hsig(acc[3][r][reg] + bi3);
            float cp = FIRST ? 0.f : creg[r][reg];
            float cv = fg * cp + ig * cg;
            creg[r][reg] = cv;
            float hv = og * ftanh(cv);
            __hip_atomic_store(hout + pix * CO + ch, hv,
                               __ATOMIC_RELAXED, __HIP_MEMORY_SCOPE_AGENT);
            out[((((size_t)b * T_ + t) * H_ + gy) * W_ + gx) * CO + ch] = hv * inv + shift;
        }
    }

    // ---- publish: all waves' stores drained by the barrier, then flag ----
    __syncthreads();
    if (tid == 0)
        __hip_atomic_store(myflag, t + 1, __ATOMIC_RELAXED, __HIP_MEMORY_SCOPE_AGENT);
}

__global__ __launch_bounds__(256, 1)
void convlstm_persist(const float* __restrict__ x,
                      const unsigned short* __restrict__ wkT,
                      const unsigned short* __restrict__ wrT,
                      const float* __restrict__ bias,
                      const float* __restrict__ gamma,
                      const float* __restrict__ beta,
                      const float* __restrict__ mean,
                      const float* __restrict__ var,
                      float* __restrict__ h0,
                      float* __restrict__ h1,
                      int* __restrict__ flags,
                      float* __restrict__ out)
{
    __shared__ __align__(16) unsigned short sx[6 * 18 * PXS];
    __shared__ __align__(16) unsigned short sh[2][6 * 18 * PXS];

    const int tid = threadIdx.x;
    const int w = tid >> 6, lane = tid & 63;
    const int ln = lane & 15, kg = lane >> 4;

    const int bi = blockIdx.x;
    const int b = bi >> 6, tile = bi & 63;
    const int ty = tile >> 2, tx = tile & 3;
    const int oy = ty * 4;               // 16 row-tiles of 4 rows
    const int ox = tx * 16;              // 4 col-tiles of 16 cols

    // neighbor flag pointer for threads 0..7 (8 spatial neighbors, same b)
    int* nbf = nullptr;
    if (tid < 8) {
        int k = tid + (tid >= 4 ? 1 : 0);         // skip center
        int dy = k / 3 - 1, dx = k - (k / 3) * 3 - 1;
        int ny = ty + dy, nx = tx + dx;
        if (ny >= 0 && ny < 16 && nx >= 0 && nx < 4)
            nbf = flags + ((b * 64 + ny * 4 + nx) << 4);
    }
    int* myflag = flags + (bi << 4);

    // per-thread epilogue constants (loop-invariant)
    const int ch = w * 16 + ln;
    const float bi0 = bias[ch], bi1 = bias[64 + ch], bi2 = bias[128 + ch], bi3 = bias[192 + ch];
    const float inv = gamma[ch] * rsqrtf(var[ch] + 1e-3f);
    const float shift = beta[ch] - mean[ch] * inv;

    const int nbase = w * 16 + ln;
    const unsigned short* wkp = wkT + (size_t)nbase * 32 + kg * 8;
    const unsigned short* wrp = wrT + (size_t)nbase * 32 + kg * 8;

    float creg[4][4];
#pragma unroll
    for (int r = 0; r < 4; ++r)
#pragma unroll
        for (int g = 0; g < 4; ++g) creg[r][g] = 0.f;

    do_step<true>(0, tid, ln, kg, b, oy, ox, x, wkp, wrp,
                  h1 /*unused*/, h0, out, sx, sh[0], sh[1], nbf, myflag,
                  bi0, bi1, bi2, bi3, inv, shift, ch, creg);

#pragma unroll 1
    for (int t = 1; t < T_; ++t) {
        float* ho = (t & 1) ? h1 : h0;
        const float* hi = (t & 1) ? h0 : h1;
        do_step<false>(t, tid, ln, kg, b, oy, ox, x, wkp, wrp,
                       hi, ho, out, sx, sh[0], sh[1], nbf, myflag,
                       bi0, bi1, bi2, bi3, inv, shift, ch, creg);
    }
}

extern "C" void kernel_launch(void* const* d_in, const int* in_sizes, int n_in,
                              void* d_out, int out_size, void* d_ws, size_t ws_size,
                              hipStream_t stream)
{
    (void)in_sizes; (void)n_in; (void)out_size; (void)ws_size;
    const float* x     = (const float*)d_in[0];
    const float* wk    = (const float*)d_in[1];
    const float* wr    = (const float*)d_in[2];
    const float* bias  = (const float*)d_in[3];
    const float* gamma = (const float*)d_in[4];
    const float* beta  = (const float*)d_in[5];
    const float* mean  = (const float*)d_in[6];
    const float* var   = (const float*)d_in[7];
    float* out = (float*)d_out;

    const size_t plane = (size_t)B_ * H_ * W_ * CO;           // 1,048,576 elems
    float* h0 = (float*)d_ws;                                 // fp32, 4 MB
    float* h1 = h0 + plane;                                   // fp32, 4 MB
    unsigned short* wkT = (unsigned short*)(h1 + plane);      // 147 KB
    unsigned short* wrT = wkT + 9 * 256 * 32;                 // 295 KB
    int* flags = (int*)(wrT + 9 * 2 * 256 * 32);              // 16 KB (256 tiles x 64 B)

    transform_weights<<<576, 256, 0, stream>>>(wk, wr, wkT, wrT, flags);
    convlstm_persist<<<256, 256, 0, stream>>>(x, wkT, wrT, bias, gamma, beta, mean, var,
                                              h0, h1, flags, out);
}

// Round 3
// 308.845 us; speedup vs baseline: 2.1075x; 2.1075x over previous
//
#include <hip/hip_runtime.h>
#include <math.h>

#define B_ 4
#define T_ 16
#define H_ 64
#define W_ 64
#define CIN 32
#define CO 64
#define NG 256   // 4*CO gate channels
#define PXS 40   // padded per-pixel stride in shorts (80 B): 16B-aligned, spreads LDS banks

typedef __attribute__((ext_vector_type(8))) short bf16x8;
typedef __attribute__((ext_vector_type(4))) float f32x4;

__device__ __forceinline__ float hsig(float z) {
    return fminf(1.f, fmaxf(0.f, 0.2f * z + 0.5f));
}

// fast tanh: v_exp_f32 + v_rcp_f32. Saturation exact at +/-inf.
__device__ __forceinline__ float ftanh(float x) {
    float e = __builtin_amdgcn_exp2f(x * 2.8853900817779268f);  // 2*log2(e)
    return 1.f - 2.f * __builtin_amdgcn_rcpf(e + 1.f);
}

__device__ __forceinline__ unsigned short f2bf(float f) {
    union { float f; unsigned u; } v; v.f = f;
    unsigned r = v.u + 0x7FFFu + ((v.u >> 16) & 1u);   // RTNE
    return (unsigned short)(r >> 16);
}

// Transpose+convert weights once per launch:
//   wkT[kpos][n=256][k=32]        from wk (3,3,32,256)
//   wrT[kpos][q=2][n=256][k=32]   from wr (3,3,64,256), q = cin chunk of 32
__global__ void transform_weights(const float* __restrict__ wk,
                                  const float* __restrict__ wr,
                                  unsigned short* __restrict__ wkT,
                                  unsigned short* __restrict__ wrT)
{
    int i = blockIdx.x * 256 + threadIdx.x;
    if (i < 9 * 256 * 32) {
        int k = i & 31, n = (i >> 5) & 255, kpos = i >> 13;
        wkT[i] = f2bf(wk[(kpos * 32 + k) * 256 + n]);
    }
    if (i < 9 * 2 * 256 * 32) {
        int k = i & 31, n = (i >> 5) & 255, q = (i >> 13) & 1, kpos = i >> 14;
        wrT[i] = f2bf(wr[(kpos * 64 + q * 32 + k) * 256 + n]);
    }
}

// One timestep. Block = 64 px (4 rows x 16 cols), 512 threads = 8 waves.
// k-split: waves 0-3 ("h-waves") do the h-conv (k=64, 288 MFMA) + epilogue;
// waves 4-7 ("x-waves") do the x-conv (k=32, 144 MFMA) and pass partials via LDS.
// Per-CU weight traffic unchanged vs the 4-wave version (each wave streams only
// its half), but 2 waves/SIMD now interleave to hide L2/L3 + LDS latency.
template<bool FIRST>
__global__ __launch_bounds__(512, 2)
void convlstm_step(const float* __restrict__ x,
                   const unsigned short* __restrict__ wkT,
                   const unsigned short* __restrict__ wrT,
                   const float* __restrict__ bias,
                   const float* __restrict__ gamma,
                   const float* __restrict__ beta,
                   const float* __restrict__ mean,
                   const float* __restrict__ var,
                   const unsigned short* __restrict__ hin,   // bf16 NHWC
                   unsigned short* __restrict__ hout,        // bf16 NHWC
                   float* __restrict__ cbuf,
                   float* __restrict__ out,
                   int t)
{
    __shared__ __align__(16) unsigned short sx[6 * 18 * PXS];        //  8.6 KB
    __shared__ __align__(16) unsigned short sh[2][6 * 18 * PXS];     // 17.3 KB
    // x-partial exchange: [slice4][gate4][row4][ch16][px 16 + 4 pad] fp32 = 80 KB
    __shared__ __align__(16) float axx[4 * 4 * 4 * 16 * 20];

    const int tid = threadIdx.x;
    const int wv = tid >> 6, lane = tid & 63;
    const int ln = lane & 15, kg = lane >> 4;
    const bool hwave = (wv < 4);
    const int sl = wv & 3;                 // n-slice: ch = sl*16 + ln

    const int bi = blockIdx.x;
    const int b = bi >> 6, tile = bi & 63;
    const int oy = (tile >> 2) * 4;        // 16 row-tiles
    const int ox = (tile & 3) * 16;        // 4 col-tiles

    // ---- parallel staging: x-waves stage sx, h-waves stage sh ----
    if (!hwave) {
        // x halo (fp32 -> bf16): 108 positions x 4 chunks of 8 cin = 432 elems
#pragma unroll
        for (int i = 0; i < 2; ++i) {
            int e = (tid - 256) + i * 256;
            if (e < 432) {
                int c8 = e & 3, p = e >> 2;
                int row = p / 18, col = p - row * 18;
                int gy = oy - 1 + row, gx = ox - 1 + col;
                float4 v0 = make_float4(0.f, 0.f, 0.f, 0.f), v1 = v0;
                if ((unsigned)gy < (unsigned)H_ && (unsigned)gx < (unsigned)W_) {
                    const float* p32 = &x[((((size_t)b * T_ + t) * H_ + gy) * W_ + gx) * CIN + c8 * 8];
                    v0 = *(const float4*)p32; v1 = *(const float4*)(p32 + 4);
                }
                unsigned short* d = &sx[(row * 18 + col) * PXS + c8 * 8];
                d[0] = f2bf(v0.x); d[1] = f2bf(v0.y); d[2] = f2bf(v0.z); d[3] = f2bf(v0.w);
                d[4] = f2bf(v1.x); d[5] = f2bf(v1.y); d[6] = f2bf(v1.z); d[7] = f2bf(v1.w);
            }
        }
    } else if (!FIRST) {
        // h halo (bf16 copy): 108 positions x 8 octs of 8 ch = 864 elems
#pragma unroll
        for (int i = 0; i < 4; ++i) {
            int e = tid + i * 256;
            if (e < 864) {
                int o = e & 7, p = e >> 3;
                int row = p / 18, col = p - row * 18;
                int gy = oy - 1 + row, gx = ox - 1 + col;
                uint4 v = make_uint4(0u, 0u, 0u, 0u);
                if ((unsigned)gy < (unsigned)H_ && (unsigned)gx < (unsigned)W_)
                    v = *(const uint4*)&hin[(((size_t)b * H_ + gy) * W_ + gx) * CO + o * 8];
                int q = o >> 2, s4 = o & 3;
                *(uint4*)&sh[q][(row * 18 + col) * PXS + s4 * 8] = v;
            }
        }
    }
    __syncthreads();

    f32x4 acc[4][4];   // [gate][row-tile]
#pragma unroll
    for (int g = 0; g < 4; ++g)
#pragma unroll
        for (int r = 0; r < 4; ++r) acc[g][r] = (f32x4){0.f, 0.f, 0.f, 0.f};

    const int nbase = sl * 16 + ln;

    if (!hwave) {
        // ---- x-conv K-loop: 9 kpos, dist-1 register prefetch of B ----
        const unsigned short* wkp = wkT + (size_t)nbase * 32 + kg * 8;
        bf16x8 bx[4];
#pragma unroll
        for (int g = 0; g < 4; ++g)
            bx[g] = *(const bf16x8*)(wkp + (size_t)(g * 64) * 32);
#pragma unroll
        for (int kpos = 0; kpos < 9; ++kpos) {
            const int ky = kpos / 3, kx = kpos - ky * 3;
            bf16x8 nbx[4];
            if (kpos < 8) {
#pragma unroll
                for (int g = 0; g < 4; ++g)
                    nbx[g] = *(const bf16x8*)(wkp + (size_t)((kpos + 1) * 256 + g * 64) * 32);
            }
            bf16x8 a[4];
#pragma unroll
            for (int r = 0; r < 4; ++r)
                a[r] = *(const bf16x8*)&sx[((r + ky) * 18 + ln + kx) * PXS + kg * 8];
#pragma unroll
            for (int g = 0; g < 4; ++g)
#pragma unroll
                for (int r = 0; r < 4; ++r)
                    acc[g][r] = __builtin_amdgcn_mfma_f32_16x16x32_bf16(a[r], bx[g], acc[g][r], 0, 0, 0);
            if (kpos < 8) {
#pragma unroll
                for (int g = 0; g < 4; ++g) bx[g] = nbx[g];
            }
        }
    } else if (!FIRST) {
        // ---- h-conv K-loop: 9 kpos x 2 cin-chunks, dist-1 prefetch ----
        const unsigned short* wrp = wrT + (size_t)nbase * 32 + kg * 8;
        bf16x8 bh[2][4];
#pragma unroll
        for (int q = 0; q < 2; ++q)
#pragma unroll
            for (int g = 0; g < 4; ++g)
                bh[q][g] = *(const bf16x8*)(wrp + (size_t)(q * 256 + g * 64) * 32);
#pragma unroll
        for (int kpos = 0; kpos < 9; ++kpos) {
            const int ky = kpos / 3, kx = kpos - ky * 3;
            bf16x8 nbh[2][4];
            if (kpos < 8) {
#pragma unroll
                for (int q = 0; q < 2; ++q)
#pragma unroll
                    for (int g = 0; g < 4; ++g)
                        nbh[q][g] = *(const bf16x8*)(wrp + (size_t)(((kpos + 1) * 2 + q) * 256 + g * 64) * 32);
            }
#pragma unroll
            for (int q = 0; q < 2; ++q) {
                bf16x8 a[4];
#pragma unroll
                for (int r = 0; r < 4; ++r)
                    a[r] = *(const bf16x8*)&sh[q][((r + ky) * 18 + ln + kx) * PXS + kg * 8];
#pragma unroll
                for (int g = 0; g < 4; ++g)
#pragma unroll
                    for (int r = 0; r < 4; ++r)
                        acc[g][r] = __builtin_amdgcn_mfma_f32_16x16x32_bf16(a[r], bh[q][g], acc[g][r], 0, 0, 0);
            }
            if (kpos < 8) {
#pragma unroll
                for (int q = 0; q < 2; ++q)
#pragma unroll
                    for (int g = 0; g < 4; ++g) bh[q][g] = nbh[q][g];
            }
        }
    }

    // ---- exchange: x-waves publish partials, h-waves consume ----
    if (!hwave) {
#pragma unroll
        for (int g = 0; g < 4; ++g)
#pragma unroll
            for (int r = 0; r < 4; ++r)
                *(f32x4*)&axx[((((sl * 4 + g) * 4 + r) * 16) + ln) * 20 + kg * 4] = acc[g][r];
    }
    __syncthreads();
    if (!hwave) return;

#pragma unroll
    for (int g = 0; g < 4; ++g)
#pragma unroll
        for (int r = 0; r < 4; ++r) {
            f32x4 v = *(const f32x4*)&axx[((((sl * 4 + g) * 4 + r) * 16) + ln) * 20 + kg * 4];
            acc[g][r] += v;
        }

    // ---- epilogue (h-waves): batch c-prev loads, then gates/BN/stores ----
    const int ch = sl * 16 + ln;
    const float bi0 = bias[ch], bi1 = bias[64 + ch], bi2 = bias[128 + ch], bi3 = bias[192 + ch];
    const float inv = gamma[ch] * rsqrtf(var[ch] + 1e-3f);
    const float shift = beta[ch] - mean[ch] * inv;

    float cprev[4][4];
    if (!FIRST) {
#pragma unroll
        for (int r = 0; r < 4; ++r)
#pragma unroll
            for (int reg = 0; reg < 4; ++reg) {
                size_t pix = ((size_t)b * H_ + oy + r) * W_ + (ox + kg * 4 + reg);
                cprev[r][reg] = cbuf[pix * CO + ch];
            }
    } else {
#pragma unroll
        for (int r = 0; r < 4; ++r)
#pragma unroll
            for (int reg = 0; reg < 4; ++reg) cprev[r][reg] = 0.f;
    }

#pragma unroll
    for (int r = 0; r < 4; ++r) {
        const int gy = oy + r;
#pragma unroll
        for (int reg = 0; reg < 4; ++reg) {
            const int gx = ox + kg * 4 + reg;
            size_t pix = ((size_t)b * H_ + gy) * W_ + gx;
            float ig = hsig(acc[0][r][reg] + bi0);
            float fg = hsig(acc[1][r][reg] + bi1);
            float cg = ftanh(acc[2][r][reg] + bi2);
            float og = hsig(acc[3][r][reg] + bi3);
            float cv = fg * cprev[r][reg] + ig * cg;
            float hv = og * ftanh(cv);
            cbuf[pix * CO + ch] = cv;
            hout[pix * CO + ch] = f2bf(hv);
            out[((((size_t)b * T_ + t) * H_ + gy) * W_ + gx) * CO + ch] = hv * inv + shift;
        }
    }
}

extern "C" void kernel_launch(void* const* d_in, const int* in_sizes, int n_in,
                              void* d_out, int out_size, void* d_ws, size_t ws_size,
                              hipStream_t stream)
{
    (void)in_sizes; (void)n_in; (void)out_size; (void)ws_size;
    const float* x     = (const float*)d_in[0];
    const float* wk    = (const float*)d_in[1];
    const float* wr    = (const float*)d_in[2];
    const float* bias  = (const float*)d_in[3];
    const float* gamma = (const float*)d_in[4];
    const float* beta  = (const float*)d_in[5];
    const float* mean  = (const float*)d_in[6];
    const float* var   = (const float*)d_in[7];
    float* out = (float*)d_out;

    const size_t plane = (size_t)B_ * H_ * W_ * CO;           // 1,048,576 elems
    unsigned short* h0 = (unsigned short*)d_ws;               // bf16, 2 MB
    unsigned short* h1 = h0 + plane;                          // bf16, 2 MB
    float* cb = (float*)(h1 + plane);                         // fp32, 4 MB
    unsigned short* wkT = (unsigned short*)(cb + plane);      // 147 KB
    unsigned short* wrT = wkT + 9 * 256 * 32;                 // 295 KB

    transform_weights<<<576, 256, 0, stream>>>(wk, wr, wkT, wrT);

    for (int t = 0; t < T_; ++t) {
        const unsigned short* hin = (t & 1) ? h0 : h1;  // garbage at t==0 (unused)
        unsigned short* houtp     = (t & 1) ? h1 : h0;
        if (t == 0)
            convlstm_step<true><<<256, 512, 0, stream>>>(x, wkT, wrT, bias, gamma, beta, mean, var,
                                                         hin, houtp, cb, out, t);
        else
            convlstm_step<false><<<256, 512, 0, stream>>>(x, wkT, wrT, bias, gamma, beta, mean, var,
                                                          hin, houtp, cb, out, t);
    }
}

// Round 4
// 288.536 us; speedup vs baseline: 2.2559x; 1.0704x over previous
//
#include <hip/hip_runtime.h>
#include <math.h>

#define B_ 4
#define T_ 16
#define H_ 64
#define W_ 64
#define CIN 32
#define CO 64
#define NG 256   // 4*CO gate channels
#define PXS 40   // padded per-pixel stride in shorts (80 B): 16B-aligned, spreads LDS banks

typedef __attribute__((ext_vector_type(8))) short bf16x8;
typedef __attribute__((ext_vector_type(4))) float f32x4;

__device__ __forceinline__ float hsig(float z) {
    return fminf(1.f, fmaxf(0.f, 0.2f * z + 0.5f));
}

// fast tanh: v_exp_f32 + v_rcp_f32. Saturation exact at +/-inf.
__device__ __forceinline__ float ftanh(float x) {
    float e = __builtin_amdgcn_exp2f(x * 2.8853900817779268f);  // 2*log2(e)
    return 1.f - 2.f * __builtin_amdgcn_rcpf(e + 1.f);
}

__device__ __forceinline__ unsigned short f2bf(float f) {
    union { float f; unsigned u; } v; v.f = f;
    unsigned r = v.u + 0x7FFFu + ((v.u >> 16) & 1u);   // RTNE
    return (unsigned short)(r >> 16);
}

// Transpose+convert weights once per launch:
//   wkT[kpos][n=256][k=32]        from wk (3,3,32,256)
//   wrT[kpos][q=2][n=256][k=32]   from wr (3,3,64,256), q = cin chunk of 32
__global__ void transform_weights(const float* __restrict__ wk,
                                  const float* __restrict__ wr,
                                  unsigned short* __restrict__ wkT,
                                  unsigned short* __restrict__ wrT)
{
    int i = blockIdx.x * 256 + threadIdx.x;
    if (i < 9 * 256 * 32) {
        int k = i & 31, n = (i >> 5) & 255, kpos = i >> 13;
        wkT[i] = f2bf(wk[(kpos * 32 + k) * 256 + n]);
    }
    if (i < 9 * 2 * 256 * 32) {
        int k = i & 31, n = (i >> 5) & 255, q = (i >> 13) & 1, kpos = i >> 14;
        wrT[i] = f2bf(wr[(kpos * 64 + q * 32 + k) * 256 + n]);
    }
}

// One timestep. Block = 64 px (4 rows x 16 cols), 512 threads = 8 waves.
// Balanced k-split over the 27 (kpos,q) chunks of the fused conv:
//   x-waves (4-7): x-conv (9 chunks) + h-conv q1 kpos 0-4 (5)  = 14 chunks
//   h-waves (0-3): h-conv q0 (9 chunks) + q1 kpos 5-8 (4)      = 13 chunks + epilogue
// Partials meet in the axx LDS exchange (weight reads stay disjoint -> per-CU
// weight traffic unchanged). 2 role-split waves/SIMD hide L2/LDS latency.
template<bool FIRST>
__global__ __launch_bounds__(512, 2)
void convlstm_step(const float* __restrict__ x,
                   const unsigned short* __restrict__ wkT,
                   const unsigned short* __restrict__ wrT,
                   const float* __restrict__ bias,
                   const float* __restrict__ gamma,
                   const float* __restrict__ beta,
                   const float* __restrict__ mean,
                   const float* __restrict__ var,
                   const unsigned short* __restrict__ hin,   // bf16 NHWC
                   unsigned short* __restrict__ hout,        // bf16 NHWC
                   float* __restrict__ cbuf,
                   float* __restrict__ out,
                   int t)
{
    __shared__ __align__(16) unsigned short sx[6 * 18 * PXS];        //  8.6 KB
    __shared__ __align__(16) unsigned short sh[2][6 * 18 * PXS];     // 17.3 KB
    // x-partial exchange: [slice4][gate4][row4][ch16][px 16 + 4 pad] fp32 = 80 KB
    __shared__ __align__(16) float axx[4 * 4 * 4 * 16 * 20];

    const int tid = threadIdx.x;
    const int wv = tid >> 6, lane = tid & 63;
    const int ln = lane & 15, kg = lane >> 4;
    const bool hwave = (wv < 4);
    const int sl = wv & 3;                 // n-slice: ch = sl*16 + ln

    const int bi = blockIdx.x;
    const int b = bi >> 6, tile = bi & 63;
    const int oy = (tile >> 2) * 4;        // 16 row-tiles
    const int ox = (tile & 3) * 16;        // 4 col-tiles

    // ---- parallel staging: x-waves stage sx, h-waves stage sh ----
    if (!hwave) {
        // x halo (fp32 -> bf16): 108 positions x 4 chunks of 8 cin = 432 elems
#pragma unroll
        for (int i = 0; i < 2; ++i) {
            int e = (tid - 256) + i * 256;
            if (e < 432) {
                int c8 = e & 3, p = e >> 2;
                int row = p / 18, col = p - row * 18;
                int gy = oy - 1 + row, gx = ox - 1 + col;
                float4 v0 = make_float4(0.f, 0.f, 0.f, 0.f), v1 = v0;
                if ((unsigned)gy < (unsigned)H_ && (unsigned)gx < (unsigned)W_) {
                    const float* p32 = &x[((((size_t)b * T_ + t) * H_ + gy) * W_ + gx) * CIN + c8 * 8];
                    v0 = *(const float4*)p32; v1 = *(const float4*)(p32 + 4);
                }
                unsigned short* d = &sx[(row * 18 + col) * PXS + c8 * 8];
                d[0] = f2bf(v0.x); d[1] = f2bf(v0.y); d[2] = f2bf(v0.z); d[3] = f2bf(v0.w);
                d[4] = f2bf(v1.x); d[5] = f2bf(v1.y); d[6] = f2bf(v1.z); d[7] = f2bf(v1.w);
            }
        }
    } else if (!FIRST) {
        // h halo (bf16 copy): 108 positions x 8 octs of 8 ch = 864 elems
#pragma unroll
        for (int i = 0; i < 4; ++i) {
            int e = tid + i * 256;
            if (e < 864) {
                int o = e & 7, p = e >> 3;
                int row = p / 18, col = p - row * 18;
                int gy = oy - 1 + row, gx = ox - 1 + col;
                uint4 v = make_uint4(0u, 0u, 0u, 0u);
                if ((unsigned)gy < (unsigned)H_ && (unsigned)gx < (unsigned)W_)
                    v = *(const uint4*)&hin[(((size_t)b * H_ + gy) * W_ + gx) * CO + o * 8];
                int q = o >> 2, s4 = o & 3;
                *(uint4*)&sh[q][(row * 18 + col) * PXS + s4 * 8] = v;
            }
        }
    }
    __syncthreads();

    const int nbase = sl * 16 + ln;
    const int ch = nbase;

    // ---- hoisted epilogue inputs (h-waves): drain under the K-loop ----
    float bi0 = 0.f, bi1 = 0.f, bi2 = 0.f, bi3 = 0.f, inv = 0.f, shift = 0.f;
    float cprev[4][4];
    if (hwave) {
        bi0 = bias[ch]; bi1 = bias[64 + ch]; bi2 = bias[128 + ch]; bi3 = bias[192 + ch];
        inv = gamma[ch] * rsqrtf(var[ch] + 1e-3f);
        shift = beta[ch] - mean[ch] * inv;
        if (!FIRST) {
#pragma unroll
            for (int r = 0; r < 4; ++r)
#pragma unroll
                for (int reg = 0; reg < 4; ++reg) {
                    size_t pix = ((size_t)b * H_ + oy + r) * W_ + (ox + kg * 4 + reg);
                    cprev[r][reg] = cbuf[pix * CO + ch];
                }
        } else {
#pragma unroll
            for (int r = 0; r < 4; ++r)
#pragma unroll
                for (int reg = 0; reg < 4; ++reg) cprev[r][reg] = 0.f;
        }
    }

    f32x4 acc[4][4];   // [gate][row-tile]
#pragma unroll
    for (int g = 0; g < 4; ++g)
#pragma unroll
        for (int r = 0; r < 4; ++r) acc[g][r] = (f32x4){0.f, 0.f, 0.f, 0.f};

    if (!hwave) {
        // ---- x-wave: x-conv (all 9 kpos) + h-conv q1 kpos 0-4 ----
        const unsigned short* wkp = wkT + (size_t)nbase * 32 + kg * 8;
        const unsigned short* wrp = wrT + (size_t)nbase * 32 + kg * 8;
        bf16x8 bx[4], bq[4];
#pragma unroll
        for (int g = 0; g < 4; ++g)
            bx[g] = *(const bf16x8*)(wkp + (size_t)(g * 64) * 32);
        if (!FIRST) {
#pragma unroll
            for (int g = 0; g < 4; ++g)
                bq[g] = *(const bf16x8*)(wrp + (size_t)(1 * 256 + g * 64) * 32);   // kpos0,q1
        }
#pragma unroll
        for (int kpos = 0; kpos < 9; ++kpos) {
            const int ky = kpos / 3, kx = kpos - ky * 3;
            bf16x8 nbx[4], nbq[4];
            if (kpos < 8) {
#pragma unroll
                for (int g = 0; g < 4; ++g)
                    nbx[g] = *(const bf16x8*)(wkp + (size_t)((kpos + 1) * 256 + g * 64) * 32);
            }
            if (!FIRST && kpos < 4) {
#pragma unroll
                for (int g = 0; g < 4; ++g)
                    nbq[g] = *(const bf16x8*)(wrp + (size_t)(((kpos + 1) * 2 + 1) * 256 + g * 64) * 32);
            }
            bf16x8 a[4];
#pragma unroll
            for (int r = 0; r < 4; ++r)
                a[r] = *(const bf16x8*)&sx[((r + ky) * 18 + ln + kx) * PXS + kg * 8];
            __builtin_amdgcn_s_setprio(1);
#pragma unroll
            for (int g = 0; g < 4; ++g)
#pragma unroll
                for (int r = 0; r < 4; ++r)
                    acc[g][r] = __builtin_amdgcn_mfma_f32_16x16x32_bf16(a[r], bx[g], acc[g][r], 0, 0, 0);
            __builtin_amdgcn_s_setprio(0);
            if (!FIRST && kpos < 5) {
#pragma unroll
                for (int r = 0; r < 4; ++r)
                    a[r] = *(const bf16x8*)&sh[1][((r + ky) * 18 + ln + kx) * PXS + kg * 8];
                __builtin_amdgcn_s_setprio(1);
#pragma unroll
                for (int g = 0; g < 4; ++g)
#pragma unroll
                    for (int r = 0; r < 4; ++r)
                        acc[g][r] = __builtin_amdgcn_mfma_f32_16x16x32_bf16(a[r], bq[g], acc[g][r], 0, 0, 0);
                __builtin_amdgcn_s_setprio(0);
            }
            if (kpos < 8) {
#pragma unroll
                for (int g = 0; g < 4; ++g) bx[g] = nbx[g];
            }
            if (!FIRST && kpos < 4) {
#pragma unroll
                for (int g = 0; g < 4; ++g) bq[g] = nbq[g];
            }
        }
    } else if (!FIRST) {
        // ---- h-wave: h-conv q0 (all 9 kpos) + q1 kpos 5-8 ----
        const unsigned short* wrp = wrT + (size_t)nbase * 32 + kg * 8;
        bf16x8 bq0[4], bq1[4];
#pragma unroll
        for (int g = 0; g < 4; ++g)
            bq0[g] = *(const bf16x8*)(wrp + (size_t)(g * 64) * 32);               // kpos0,q0
#pragma unroll
        for (int kpos = 0; kpos < 9; ++kpos) {
            const int ky = kpos / 3, kx = kpos - ky * 3;
            bf16x8 nbq0[4], nbq1[4];
            if (kpos < 8) {
#pragma unroll
                for (int g = 0; g < 4; ++g)
                    nbq0[g] = *(const bf16x8*)(wrp + (size_t)((kpos + 1) * 2 * 256 + g * 64) * 32);
            }
            if (kpos >= 4 && kpos < 8) {
#pragma unroll
                for (int g = 0; g < 4; ++g)
                    nbq1[g] = *(const bf16x8*)(wrp + (size_t)(((kpos + 1) * 2 + 1) * 256 + g * 64) * 32);
            }
            bf16x8 a[4];
#pragma unroll
            for (int r = 0; r < 4; ++r)
                a[r] = *(const bf16x8*)&sh[0][((r + ky) * 18 + ln + kx) * PXS + kg * 8];
            __builtin_amdgcn_s_setprio(1);
#pragma unroll
            for (int g = 0; g < 4; ++g)
#pragma unroll
                for (int r = 0; r < 4; ++r)
                    acc[g][r] = __builtin_amdgcn_mfma_f32_16x16x32_bf16(a[r], bq0[g], acc[g][r], 0, 0, 0);
            __builtin_amdgcn_s_setprio(0);
            if (kpos >= 5) {
#pragma unroll
                for (int r = 0; r < 4; ++r)
                    a[r] = *(const bf16x8*)&sh[1][((r + ky) * 18 + ln + kx) * PXS + kg * 8];
                __builtin_amdgcn_s_setprio(1);
#pragma unroll
                for (int g = 0; g < 4; ++g)
#pragma unroll
                    for (int r = 0; r < 4; ++r)
                        acc[g][r] = __builtin_amdgcn_mfma_f32_16x16x32_bf16(a[r], bq1[g], acc[g][r], 0, 0, 0);
                __builtin_amdgcn_s_setprio(0);
            }
            if (kpos < 8) {
#pragma unroll
                for (int g = 0; g < 4; ++g) bq0[g] = nbq0[g];
            }
            if (kpos >= 4 && kpos < 8) {
#pragma unroll
                for (int g = 0; g < 4; ++g) bq1[g] = nbq1[g];
            }
        }
    }

    // ---- exchange: x-waves publish partials, h-waves consume ----
    if (!hwave) {
#pragma unroll
        for (int g = 0; g < 4; ++g)
#pragma unroll
            for (int r = 0; r < 4; ++r)
                *(f32x4*)&axx[((((sl * 4 + g) * 4 + r) * 16) + ln) * 20 + kg * 4] = acc[g][r];
    }
    __syncthreads();
    if (!hwave) return;

#pragma unroll
    for (int g = 0; g < 4; ++g)
#pragma unroll
        for (int r = 0; r < 4; ++r) {
            f32x4 v = *(const f32x4*)&axx[((((sl * 4 + g) * 4 + r) * 16) + ln) * 20 + kg * 4];
            acc[g][r] += v;
        }

    // ---- epilogue (h-waves): gates/BN/stores; out & cbuf bypass L2 (nt) ----
#pragma unroll
    for (int r = 0; r < 4; ++r) {
        const int gy = oy + r;
#pragma unroll
        for (int reg = 0; reg < 4; ++reg) {
            const int gx = ox + kg * 4 + reg;
            size_t pix = ((size_t)b * H_ + gy) * W_ + gx;
            float ig = hsig(acc[0][r][reg] + bi0);
            float fg = hsig(acc[1][r][reg] + bi1);
            float cg = ftanh(acc[2][r][reg] + bi2);
            float og = hsig(acc[3][r][reg] + bi3);
            float cv = fg * cprev[r][reg] + ig * cg;
            float hv = og * ftanh(cv);
            __builtin_nontemporal_store(cv, &cbuf[pix * CO + ch]);
            hout[pix * CO + ch] = f2bf(hv);
            __builtin_nontemporal_store(hv * inv + shift,
                &out[((((size_t)b * T_ + t) * H_ + gy) * W_ + gx) * CO + ch]);
        }
    }
}

extern "C" void kernel_launch(void* const* d_in, const int* in_sizes, int n_in,
                              void* d_out, int out_size, void* d_ws, size_t ws_size,
                              hipStream_t stream)
{
    (void)in_sizes; (void)n_in; (void)out_size; (void)ws_size;
    const float* x     = (const float*)d_in[0];
    const float* wk    = (const float*)d_in[1];
    const float* wr    = (const float*)d_in[2];
    const float* bias  = (const float*)d_in[3];
    const float* gamma = (const float*)d_in[4];
    const float* beta  = (const float*)d_in[5];
    const float* mean  = (const float*)d_in[6];
    const float* var   = (const float*)d_in[7];
    float* out = (float*)d_out;

    const size_t plane = (size_t)B_ * H_ * W_ * CO;           // 1,048,576 elems
    unsigned short* h0 = (unsigned short*)d_ws;               // bf16, 2 MB
    unsigned short* h1 = h0 + plane;                          // bf16, 2 MB
    float* cb = (float*)(h1 + plane);                         // fp32, 4 MB
    unsigned short* wkT = (unsigned short*)(cb + plane);      // 147 KB
    unsigned short* wrT = wkT + 9 * 256 * 32;                 // 295 KB

    transform_weights<<<576, 256, 0, stream>>>(wk, wr, wkT, wrT);

    for (int t = 0; t < T_; ++t) {
        const unsigned short* hin = (t & 1) ? h0 : h1;  // garbage at t==0 (unused)
        unsigned short* houtp     = (t & 1) ? h1 : h0;
        if (t == 0)
            convlstm_step<true><<<256, 512, 0, stream>>>(x, wkT, wrT, bias, gamma, beta, mean, var,
                                                         hin, houtp, cb, out, t);
        else
            convlstm_step<false><<<256, 512, 0, stream>>>(x, wkT, wrT, bias, gamma, beta, mean, var,
                                                          hin, houtp, cb, out, t);
    }
}